// Round 2
// baseline (4562.966 us; speedup 1.0000x reference)
//
#include <hip/hip_runtime.h>
#include <hip/hip_bf16.h>

#define H 16
#define NW 20

__device__ __forceinline__ float bf2f(unsigned short u) {
    union { unsigned int u; float f; } c; c.u = ((unsigned int)u) << 16; return c.f;
}

__device__ __forceinline__ float bf_round(float f) {
    // round-to-nearest-even to bf16, return as f32
    return __bfloat162float(__float2bfloat16(f));
}

// ---------------- weight conversion: bf16 -> f32 staging ----------------
struct WPtrs { const unsigned short* src[NW]; int len[NW]; int off[NW]; };

__global__ void cvt_weights_kernel(WPtrs p, float* __restrict__ dst) {
    int a = blockIdx.x;
    const unsigned short* s = p.src[a];
    float* d = dst + p.off[a];
    int n = p.len[a];
    for (int t = threadIdx.x; t < n; t += blockDim.x) d[t] = bf2f(s[t]);
}

// ---------------- encoder: scalar -> h -> h MLP ----------------
__global__ __launch_bounds__(256) void encode_kernel(
    const unsigned short* __restrict__ xin, int n,
    const float* __restrict__ W1, const float* __restrict__ b1,
    const float* __restrict__ W2, const float* __restrict__ b2,
    float* __restrict__ out)
{
    int i = blockIdx.x * blockDim.x + threadIdx.x;
    if (i >= n) return;
    float v = bf2f(xin[i]);
    float h[H];
    #pragma unroll
    for (int o = 0; o < H; ++o) {
        float t = W1[o] * v + b1[o];
        h[o] = t > 0.f ? t : 0.f;
    }
    float acc[H];
    #pragma unroll
    for (int o = 0; o < H; ++o) acc[o] = b2[o];
    #pragma unroll
    for (int k = 0; k < H; ++k) {
        float hk = h[k];
        #pragma unroll
        for (int o = 0; o < H; ++o) acc[o] += W2[o * H + k] * hk;
    }
    float4* dst = (float4*)(out + (size_t)i * H);
    dst[0] = make_float4(acc[0], acc[1], acc[2], acc[3]);
    dst[1] = make_float4(acc[4], acc[5], acc[6], acc[7]);
    dst[2] = make_float4(acc[8], acc[9], acc[10], acc[11]);
    dst[3] = make_float4(acc[12], acc[13], acc[14], acc[15]);
}

// ---------------- degree (count of edges per receiver) ----------------
__global__ __launch_bounds__(256) void deg_kernel(
    const int* __restrict__ recv, int n_edges, float* __restrict__ deg)
{
    int e = blockIdx.x * blockDim.x + threadIdx.x;
    if (e < n_edges) atomicAdd(&deg[recv[e]], 1.0f);
}

// ---------------- edge update: MLP(concat[nf_s, nf_r, ef]) + fused scatter ----------------
__global__ __launch_bounds__(256) void edge_update_kernel(
    const float* __restrict__ nf, float* __restrict__ ef,
    const int* __restrict__ senders, const int* __restrict__ recv, int n_edges,
    const float* __restrict__ W1, const float* __restrict__ b1,
    const float* __restrict__ W2, const float* __restrict__ b2,
    float* __restrict__ agg)
{
    int e = blockIdx.x * blockDim.x + threadIdx.x;
    if (e >= n_edges) return;
    int s = senders[e], r = recv[e];
    float x[3 * H];
    const float4* ps = (const float4*)(nf + (size_t)s * H);
    const float4* pr = (const float4*)(nf + (size_t)r * H);
    const float4* pe = (const float4*)(ef + (size_t)e * H);
    #pragma unroll
    for (int q = 0; q < 4; ++q) {
        float4 v = ps[q];
        x[q*4+0] = v.x; x[q*4+1] = v.y; x[q*4+2] = v.z; x[q*4+3] = v.w;
    }
    #pragma unroll
    for (int q = 0; q < 4; ++q) {
        float4 v = pr[q];
        x[16+q*4+0] = v.x; x[16+q*4+1] = v.y; x[16+q*4+2] = v.z; x[16+q*4+3] = v.w;
    }
    #pragma unroll
    for (int q = 0; q < 4; ++q) {
        float4 v = pe[q];
        x[32+q*4+0] = v.x; x[32+q*4+1] = v.y; x[32+q*4+2] = v.z; x[32+q*4+3] = v.w;
    }
    float h[H];
    #pragma unroll
    for (int o = 0; o < H; ++o) h[o] = b1[o];
    #pragma unroll
    for (int k = 0; k < 3 * H; ++k) {
        float xk = x[k];
        #pragma unroll
        for (int o = 0; o < H; ++o) h[o] += W1[o * 3 * H + k] * xk;
    }
    #pragma unroll
    for (int o = 0; o < H; ++o) h[o] = h[o] > 0.f ? h[o] : 0.f;
    float acc[H];
    #pragma unroll
    for (int o = 0; o < H; ++o) acc[o] = b2[o];
    #pragma unroll
    for (int k = 0; k < H; ++k) {
        float hk = h[k];
        #pragma unroll
        for (int o = 0; o < H; ++o) acc[o] += W2[o * H + k] * hk;
    }
    float4* dst = (float4*)(ef + (size_t)e * H);
    dst[0] = make_float4(acc[0], acc[1], acc[2], acc[3]);
    dst[1] = make_float4(acc[4], acc[5], acc[6], acc[7]);
    dst[2] = make_float4(acc[8], acc[9], acc[10], acc[11]);
    dst[3] = make_float4(acc[12], acc[13], acc[14], acc[15]);
    float* ag = agg + (size_t)r * H;
    #pragma unroll
    for (int f = 0; f < H; ++f) atomicAdd(&ag[f], acc[f]);
}

// ---------------- node update: MLP(concat[nf, agg/deg]) ----------------
__global__ __launch_bounds__(256) void node_update_kernel(
    float* __restrict__ nf, const float* __restrict__ agg,
    const float* __restrict__ deg, int n_nodes,
    const float* __restrict__ W1, const float* __restrict__ b1,
    const float* __restrict__ W2, const float* __restrict__ b2)
{
    int i = blockIdx.x * blockDim.x + threadIdx.x;
    if (i >= n_nodes) return;
    float x[2 * H];
    const float4* pn = (const float4*)(nf + (size_t)i * H);
    const float4* pa = (const float4*)(agg + (size_t)i * H);
    #pragma unroll
    for (int q = 0; q < 4; ++q) {
        float4 v = pn[q];
        x[q*4+0] = v.x; x[q*4+1] = v.y; x[q*4+2] = v.z; x[q*4+3] = v.w;
    }
    float d = deg[i];
    float rd = 1.0f / (d > 1.0f ? d : 1.0f);
    #pragma unroll
    for (int q = 0; q < 4; ++q) {
        float4 v = pa[q];
        x[16+q*4+0] = v.x * rd; x[16+q*4+1] = v.y * rd;
        x[16+q*4+2] = v.z * rd; x[16+q*4+3] = v.w * rd;
    }
    float h[H];
    #pragma unroll
    for (int o = 0; o < H; ++o) h[o] = b1[o];
    #pragma unroll
    for (int k = 0; k < 2 * H; ++k) {
        float xk = x[k];
        #pragma unroll
        for (int o = 0; o < H; ++o) h[o] += W1[o * 2 * H + k] * xk;
    }
    #pragma unroll
    for (int o = 0; o < H; ++o) h[o] = h[o] > 0.f ? h[o] : 0.f;
    float acc[H];
    #pragma unroll
    for (int o = 0; o < H; ++o) acc[o] = b2[o];
    #pragma unroll
    for (int k = 0; k < H; ++k) {
        float hk = h[k];
        #pragma unroll
        for (int o = 0; o < H; ++o) acc[o] += W2[o * H + k] * hk;
    }
    float4* dst = (float4*)(nf + (size_t)i * H);
    dst[0] = make_float4(acc[0], acc[1], acc[2], acc[3]);
    dst[1] = make_float4(acc[4], acc[5], acc[6], acc[7]);
    dst[2] = make_float4(acc[8], acc[9], acc[10], acc[11]);
    dst[3] = make_float4(acc[12], acc[13], acc[14], acc[15]);
}

// ---------------- bidirectional edge averaging (in place) ----------------
__global__ __launch_bounds__(256) void bi_avg_kernel(
    float* __restrict__ ef, const int* __restrict__ bi, int n_bi)
{
    int p = blockIdx.x * blockDim.x + threadIdx.x;
    if (p >= n_bi) return;
    int i = bi[p], j = bi[n_bi + p];
    float4* pi = (float4*)(ef + (size_t)i * H);
    float4* pj = (float4*)(ef + (size_t)j * H);
    #pragma unroll
    for (int q = 0; q < 4; ++q) {
        float4 a = pi[q], b = pj[q];
        float4 m = make_float4(0.5f*(a.x+b.x), 0.5f*(a.y+b.y),
                               0.5f*(a.z+b.z), 0.5f*(a.w+b.w));
        pi[q] = m; pj[q] = m;
    }
}

// ---------------- decoder: h -> h -> 1, tril mask, emit f32 outputs ----------------
__global__ __launch_bounds__(256) void decode_kernel(
    const float* __restrict__ ef, const int* __restrict__ recv,
    const int* __restrict__ send, int n_edges,
    const float* __restrict__ W1, const float* __restrict__ b1,
    const float* __restrict__ W2, const float* __restrict__ b2,
    float* __restrict__ out)
{
    int e = blockIdx.x * blockDim.x + threadIdx.x;
    if (e >= n_edges) return;
    float x[H];
    const float4* pe = (const float4*)(ef + (size_t)e * H);
    #pragma unroll
    for (int q = 0; q < 4; ++q) {
        float4 v = pe[q];
        x[q*4+0] = v.x; x[q*4+1] = v.y; x[q*4+2] = v.z; x[q*4+3] = v.w;
    }
    float h[H];
    #pragma unroll
    for (int o = 0; o < H; ++o) h[o] = b1[o];
    #pragma unroll
    for (int k = 0; k < H; ++k) {
        float xk = x[k];
        #pragma unroll
        for (int o = 0; o < H; ++o) h[o] += W1[o * H + k] * xk;
    }
    float val = b2[0];
    #pragma unroll
    for (int k = 0; k < H; ++k) {
        float hk = h[k] > 0.f ? h[k] : 0.f;
        val += W2[k] * hk;
    }
    int r = recv[e], s = send[e];
    val = (r >= s) ? val : 0.0f;
    // d_out is a flat f32 buffer; reference arrays are bf16-rounded, so
    // round-trip the indices through bf16 to match exactly.
    out[e] = val;
    out[(size_t)n_edges + e] = bf_round((float)r);
    out[2 * (size_t)n_edges + e] = bf_round((float)s);
}

// ---------------- host launcher ----------------
extern "C" void kernel_launch(void* const* d_in, const int* in_sizes, int n_in,
                              void* d_out, int out_size, void* d_ws, size_t ws_size,
                              hipStream_t stream) {
    const unsigned short* nodes = (const unsigned short*)d_in[0];
    const unsigned short* edges = (const unsigned short*)d_in[1];
    const int* receivers = (const int*)d_in[2];
    const int* senders   = (const int*)d_in[3];
    const int* bi        = (const int*)d_in[4];
    const int n_nodes = in_sizes[0];
    const int n_edges = in_sizes[1];
    const int n_bi    = in_sizes[4] / 2;

    static const int wl[NW] = {16,16,256,16, 16,16,256,16,
                               3840,80,1280,80, 2560,80,1280,80,
                               256,16,16,1};
    WPtrs wp;
    {
        int off = 0;
        for (int a = 0; a < NW; ++a) {
            wp.src[a] = (const unsigned short*)d_in[5 + a];
            wp.len[a] = wl[a];
            wp.off[a] = off;
            off += wl[a];
        }
    }
    float* wf = (float*)d_ws;
    const float* Wf[NW];
    for (int a = 0; a < NW; ++a) Wf[a] = wf + wp.off[a];

    float* nf  = wf + 10240;                      // [n_nodes][16] f32
    float* ef  = nf + (size_t)n_nodes * H;        // [n_edges][16] f32
    float* agg = ef + (size_t)n_edges * H;        // [n_nodes][16] f32
    float* deg = agg + (size_t)n_nodes * H;       // [n_nodes] f32

    const int bn = 256;
    cvt_weights_kernel<<<NW, 256, 0, stream>>>(wp, wf);
    encode_kernel<<<(n_nodes + bn - 1) / bn, bn, 0, stream>>>(
        nodes, n_nodes, Wf[0], Wf[1], Wf[2], Wf[3], nf);
    encode_kernel<<<(n_edges + bn - 1) / bn, bn, 0, stream>>>(
        edges, n_edges, Wf[4], Wf[5], Wf[6], Wf[7], ef);
    hipMemsetAsync(deg, 0, (size_t)n_nodes * 4, stream);
    deg_kernel<<<(n_edges + bn - 1) / bn, bn, 0, stream>>>(receivers, n_edges, deg);

    for (int r = 0; r < 5; ++r) {
        hipMemsetAsync(agg, 0, (size_t)n_nodes * H * 4, stream);
        edge_update_kernel<<<(n_edges + bn - 1) / bn, bn, 0, stream>>>(
            nf, ef, senders, receivers, n_edges,
            Wf[8] + r * 3 * H * H, Wf[9] + r * H,
            Wf[10] + r * H * H,    Wf[11] + r * H, agg);
        node_update_kernel<<<(n_nodes + bn - 1) / bn, bn, 0, stream>>>(
            nf, agg, deg, n_nodes,
            Wf[12] + r * 2 * H * H, Wf[13] + r * H,
            Wf[14] + r * H * H,     Wf[15] + r * H);
    }

    bi_avg_kernel<<<(n_bi + bn - 1) / bn, bn, 0, stream>>>(ef, bi, n_bi);
    decode_kernel<<<(n_edges + bn - 1) / bn, bn, 0, stream>>>(
        ef, receivers, senders, n_edges,
        Wf[16], Wf[17], Wf[18], Wf[19], (float*)d_out);
}

// Round 3
// 1075.570 us; speedup vs baseline: 4.2424x; 4.2424x over previous
//
#include <hip/hip_runtime.h>
#include <hip/hip_bf16.h>

#define H 16
#define NW 20

__device__ __forceinline__ float bf2f(unsigned short u) {
    union { unsigned int u; float f; } c; c.u = ((unsigned int)u) << 16; return c.f;
}

__device__ __forceinline__ float bf_round(float f) {
    return __bfloat162float(__float2bfloat16(f));
}

// ---------------- weight conversion: bf16 -> f32 staging ----------------
struct WPtrs { const unsigned short* src[NW]; int len[NW]; int off[NW]; };

__global__ void cvt_weights_kernel(WPtrs p, float* __restrict__ dst) {
    int a = blockIdx.x;
    const unsigned short* s = p.src[a];
    float* d = dst + p.off[a];
    int n = p.len[a];
    for (int t = threadIdx.x; t < n; t += blockDim.x) d[t] = bf2f(s[t]);
}

// ---------------- encoder: scalar -> h -> h MLP ----------------
__global__ __launch_bounds__(256) void encode_kernel(
    const unsigned short* __restrict__ xin, int n,
    const float* __restrict__ W1, const float* __restrict__ b1,
    const float* __restrict__ W2, const float* __restrict__ b2,
    float* __restrict__ out)
{
    int i = blockIdx.x * blockDim.x + threadIdx.x;
    if (i >= n) return;
    float v = bf2f(xin[i]);
    float h[H];
    #pragma unroll
    for (int o = 0; o < H; ++o) {
        float t = W1[o] * v + b1[o];
        h[o] = t > 0.f ? t : 0.f;
    }
    float acc[H];
    #pragma unroll
    for (int o = 0; o < H; ++o) acc[o] = b2[o];
    #pragma unroll
    for (int k = 0; k < H; ++k) {
        float hk = h[k];
        #pragma unroll
        for (int o = 0; o < H; ++o) acc[o] += W2[o * H + k] * hk;
    }
    float4* dst = (float4*)(out + (size_t)i * H);
    dst[0] = make_float4(acc[0], acc[1], acc[2], acc[3]);
    dst[1] = make_float4(acc[4], acc[5], acc[6], acc[7]);
    dst[2] = make_float4(acc[8], acc[9], acc[10], acc[11]);
    dst[3] = make_float4(acc[12], acc[13], acc[14], acc[15]);
}

// ---------------- CSR build: histogram -> scan -> fill ----------------
__global__ __launch_bounds__(256) void hist_kernel(
    const int* __restrict__ recv, int n_edges, int* __restrict__ cnt)
{
    int e = blockIdx.x * blockDim.x + threadIdx.x;
    if (e < n_edges) atomicAdd(&cnt[recv[e]], 1);
}

// single-block exclusive scan over n counters (n up to ~1M with 1024 threads)
__global__ __launch_bounds__(1024) void scan_kernel(
    const int* __restrict__ cnt, int n,
    int* __restrict__ row_start, int* __restrict__ cursor)
{
    __shared__ int sums[1024];
    int t = threadIdx.x;
    int chunk = (n + 1023) / 1024;
    int lo = t * chunk;
    int hi = lo + chunk; if (hi > n) hi = n;
    if (lo > n) lo = n;
    int s = 0;
    for (int i = lo; i < hi; ++i) s += cnt[i];
    sums[t] = s;
    __syncthreads();
    // inclusive Hillis-Steele scan
    for (int off = 1; off < 1024; off <<= 1) {
        int v = (t >= off) ? sums[t - off] : 0;
        __syncthreads();
        sums[t] += v;
        __syncthreads();
    }
    int run = sums[t] - s;  // exclusive base for this thread's chunk
    for (int i = lo; i < hi; ++i) {
        row_start[i] = run;
        cursor[i] = run;
        run += cnt[i];
    }
    if (hi == n && lo < n) row_start[n] = run;
    if (t == 0 && n == 0) row_start[0] = 0;
}

__global__ __launch_bounds__(256) void fill_kernel(
    const int* __restrict__ recv, int n_edges,
    int* __restrict__ cursor, int* __restrict__ elist)
{
    int e = blockIdx.x * blockDim.x + threadIdx.x;
    if (e >= n_edges) return;
    int pos = atomicAdd(&cursor[recv[e]], 1);
    elist[pos] = e;
}

// ---------------- edge update: MLP(concat[nf_s, nf_r, ef]), no scatter ----------------
__global__ __launch_bounds__(256) void edge_update_kernel(
    const float* __restrict__ nf, float* __restrict__ ef,
    const int* __restrict__ senders, const int* __restrict__ recv, int n_edges,
    const float* __restrict__ W1, const float* __restrict__ b1,
    const float* __restrict__ W2, const float* __restrict__ b2)
{
    int e = blockIdx.x * blockDim.x + threadIdx.x;
    if (e >= n_edges) return;
    int s = senders[e], r = recv[e];
    float x[3 * H];
    const float4* ps = (const float4*)(nf + (size_t)s * H);
    const float4* pr = (const float4*)(nf + (size_t)r * H);
    const float4* pe = (const float4*)(ef + (size_t)e * H);
    #pragma unroll
    for (int q = 0; q < 4; ++q) {
        float4 v = ps[q];
        x[q*4+0] = v.x; x[q*4+1] = v.y; x[q*4+2] = v.z; x[q*4+3] = v.w;
    }
    #pragma unroll
    for (int q = 0; q < 4; ++q) {
        float4 v = pr[q];
        x[16+q*4+0] = v.x; x[16+q*4+1] = v.y; x[16+q*4+2] = v.z; x[16+q*4+3] = v.w;
    }
    #pragma unroll
    for (int q = 0; q < 4; ++q) {
        float4 v = pe[q];
        x[32+q*4+0] = v.x; x[32+q*4+1] = v.y; x[32+q*4+2] = v.z; x[32+q*4+3] = v.w;
    }
    float h[H];
    #pragma unroll
    for (int o = 0; o < H; ++o) h[o] = b1[o];
    #pragma unroll
    for (int k = 0; k < 3 * H; ++k) {
        float xk = x[k];
        #pragma unroll
        for (int o = 0; o < H; ++o) h[o] += W1[o * 3 * H + k] * xk;
    }
    #pragma unroll
    for (int o = 0; o < H; ++o) h[o] = h[o] > 0.f ? h[o] : 0.f;
    float acc[H];
    #pragma unroll
    for (int o = 0; o < H; ++o) acc[o] = b2[o];
    #pragma unroll
    for (int k = 0; k < H; ++k) {
        float hk = h[k];
        #pragma unroll
        for (int o = 0; o < H; ++o) acc[o] += W2[o * H + k] * hk;
    }
    float4* dst = (float4*)(ef + (size_t)e * H);
    dst[0] = make_float4(acc[0], acc[1], acc[2], acc[3]);
    dst[1] = make_float4(acc[4], acc[5], acc[6], acc[7]);
    dst[2] = make_float4(acc[8], acc[9], acc[10], acc[11]);
    dst[3] = make_float4(acc[12], acc[13], acc[14], acc[15]);
}

// ---------------- node update: gather incoming ef via CSR, then MLP ----------------
__global__ __launch_bounds__(256) void node_update_kernel(
    float* __restrict__ nf, const float* __restrict__ ef,
    const int* __restrict__ row_start, const int* __restrict__ elist, int n_nodes,
    const float* __restrict__ W1, const float* __restrict__ b1,
    const float* __restrict__ W2, const float* __restrict__ b2)
{
    int i = blockIdx.x * blockDim.x + threadIdx.x;
    if (i >= n_nodes) return;
    int lo = row_start[i], hi = row_start[i + 1];
    float a[H];
    #pragma unroll
    for (int o = 0; o < H; ++o) a[o] = 0.f;
    for (int j = lo; j < hi; ++j) {
        int e = elist[j];
        const float4* pe = (const float4*)(ef + (size_t)e * H);
        float4 v0 = pe[0], v1 = pe[1], v2 = pe[2], v3 = pe[3];
        a[0] += v0.x; a[1] += v0.y; a[2] += v0.z; a[3] += v0.w;
        a[4] += v1.x; a[5] += v1.y; a[6] += v1.z; a[7] += v1.w;
        a[8] += v2.x; a[9] += v2.y; a[10] += v2.z; a[11] += v2.w;
        a[12] += v3.x; a[13] += v3.y; a[14] += v3.z; a[15] += v3.w;
    }
    int d = hi - lo;
    float rd = 1.0f / (float)(d > 1 ? d : 1);
    float x[2 * H];
    const float4* pn = (const float4*)(nf + (size_t)i * H);
    #pragma unroll
    for (int q = 0; q < 4; ++q) {
        float4 v = pn[q];
        x[q*4+0] = v.x; x[q*4+1] = v.y; x[q*4+2] = v.z; x[q*4+3] = v.w;
    }
    #pragma unroll
    for (int o = 0; o < H; ++o) x[16 + o] = a[o] * rd;
    float h[H];
    #pragma unroll
    for (int o = 0; o < H; ++o) h[o] = b1[o];
    #pragma unroll
    for (int k = 0; k < 2 * H; ++k) {
        float xk = x[k];
        #pragma unroll
        for (int o = 0; o < H; ++o) h[o] += W1[o * 2 * H + k] * xk;
    }
    #pragma unroll
    for (int o = 0; o < H; ++o) h[o] = h[o] > 0.f ? h[o] : 0.f;
    float acc[H];
    #pragma unroll
    for (int o = 0; o < H; ++o) acc[o] = b2[o];
    #pragma unroll
    for (int k = 0; k < H; ++k) {
        float hk = h[k];
        #pragma unroll
        for (int o = 0; o < H; ++o) acc[o] += W2[o * H + k] * hk;
    }
    float4* dst = (float4*)(nf + (size_t)i * H);
    dst[0] = make_float4(acc[0], acc[1], acc[2], acc[3]);
    dst[1] = make_float4(acc[4], acc[5], acc[6], acc[7]);
    dst[2] = make_float4(acc[8], acc[9], acc[10], acc[11]);
    dst[3] = make_float4(acc[12], acc[13], acc[14], acc[15]);
}

// ---------------- bidirectional edge averaging (in place) ----------------
__global__ __launch_bounds__(256) void bi_avg_kernel(
    float* __restrict__ ef, const int* __restrict__ bi, int n_bi)
{
    int p = blockIdx.x * blockDim.x + threadIdx.x;
    if (p >= n_bi) return;
    int i = bi[p], j = bi[n_bi + p];
    float4* pi = (float4*)(ef + (size_t)i * H);
    float4* pj = (float4*)(ef + (size_t)j * H);
    #pragma unroll
    for (int q = 0; q < 4; ++q) {
        float4 a = pi[q], b = pj[q];
        float4 m = make_float4(0.5f*(a.x+b.x), 0.5f*(a.y+b.y),
                               0.5f*(a.z+b.z), 0.5f*(a.w+b.w));
        pi[q] = m; pj[q] = m;
    }
}

// ---------------- decoder: h -> h -> 1, tril mask, emit f32 outputs ----------------
__global__ __launch_bounds__(256) void decode_kernel(
    const float* __restrict__ ef, const int* __restrict__ recv,
    const int* __restrict__ send, int n_edges,
    const float* __restrict__ W1, const float* __restrict__ b1,
    const float* __restrict__ W2, const float* __restrict__ b2,
    float* __restrict__ out)
{
    int e = blockIdx.x * blockDim.x + threadIdx.x;
    if (e >= n_edges) return;
    float x[H];
    const float4* pe = (const float4*)(ef + (size_t)e * H);
    #pragma unroll
    for (int q = 0; q < 4; ++q) {
        float4 v = pe[q];
        x[q*4+0] = v.x; x[q*4+1] = v.y; x[q*4+2] = v.z; x[q*4+3] = v.w;
    }
    float h[H];
    #pragma unroll
    for (int o = 0; o < H; ++o) h[o] = b1[o];
    #pragma unroll
    for (int k = 0; k < H; ++k) {
        float xk = x[k];
        #pragma unroll
        for (int o = 0; o < H; ++o) h[o] += W1[o * H + k] * xk;
    }
    float val = b2[0];
    #pragma unroll
    for (int k = 0; k < H; ++k) {
        float hk = h[k] > 0.f ? h[k] : 0.f;
        val += W2[k] * hk;
    }
    int r = recv[e], s = send[e];
    val = (r >= s) ? val : 0.0f;
    out[e] = val;
    out[(size_t)n_edges + e] = bf_round((float)r);
    out[2 * (size_t)n_edges + e] = bf_round((float)s);
}

// ---------------- host launcher ----------------
extern "C" void kernel_launch(void* const* d_in, const int* in_sizes, int n_in,
                              void* d_out, int out_size, void* d_ws, size_t ws_size,
                              hipStream_t stream) {
    const unsigned short* nodes = (const unsigned short*)d_in[0];
    const unsigned short* edges = (const unsigned short*)d_in[1];
    const int* receivers = (const int*)d_in[2];
    const int* senders   = (const int*)d_in[3];
    const int* bi        = (const int*)d_in[4];
    const int n_nodes = in_sizes[0];
    const int n_edges = in_sizes[1];
    const int n_bi    = in_sizes[4] / 2;

    static const int wl[NW] = {16,16,256,16, 16,16,256,16,
                               3840,80,1280,80, 2560,80,1280,80,
                               256,16,16,1};
    WPtrs wp;
    {
        int off = 0;
        for (int a = 0; a < NW; ++a) {
            wp.src[a] = (const unsigned short*)d_in[5 + a];
            wp.len[a] = wl[a];
            wp.off[a] = off;
            off += wl[a];
        }
    }
    float* wf = (float*)d_ws;
    const float* Wf[NW];
    for (int a = 0; a < NW; ++a) Wf[a] = wf + wp.off[a];

    float* nf  = wf + 10240;                       // [n_nodes][16] f32
    float* ef  = nf + (size_t)n_nodes * H;         // [n_edges][16] f32
    int* cnt       = (int*)(ef + (size_t)n_edges * H); // [n_nodes]
    int* row_start = cnt + n_nodes;                // [n_nodes+1]
    int* cursor    = row_start + n_nodes + 1;      // [n_nodes]
    int* elist     = cursor + n_nodes;             // [n_edges]

    const int bn = 256;
    cvt_weights_kernel<<<NW, 256, 0, stream>>>(wp, wf);
    encode_kernel<<<(n_nodes + bn - 1) / bn, bn, 0, stream>>>(
        nodes, n_nodes, Wf[0], Wf[1], Wf[2], Wf[3], nf);
    encode_kernel<<<(n_edges + bn - 1) / bn, bn, 0, stream>>>(
        edges, n_edges, Wf[4], Wf[5], Wf[6], Wf[7], ef);

    // CSR build (once per launch; receivers are fixed input)
    hipMemsetAsync(cnt, 0, (size_t)n_nodes * 4, stream);
    hist_kernel<<<(n_edges + bn - 1) / bn, bn, 0, stream>>>(receivers, n_edges, cnt);
    scan_kernel<<<1, 1024, 0, stream>>>(cnt, n_nodes, row_start, cursor);
    fill_kernel<<<(n_edges + bn - 1) / bn, bn, 0, stream>>>(receivers, n_edges, cursor, elist);

    for (int r = 0; r < 5; ++r) {
        edge_update_kernel<<<(n_edges + bn - 1) / bn, bn, 0, stream>>>(
            nf, ef, senders, receivers, n_edges,
            Wf[8] + r * 3 * H * H, Wf[9] + r * H,
            Wf[10] + r * H * H,    Wf[11] + r * H);
        node_update_kernel<<<(n_nodes + bn - 1) / bn, bn, 0, stream>>>(
            nf, ef, row_start, elist, n_nodes,
            Wf[12] + r * 2 * H * H, Wf[13] + r * H,
            Wf[14] + r * H * H,     Wf[15] + r * H);
    }

    bi_avg_kernel<<<(n_bi + bn - 1) / bn, bn, 0, stream>>>(ef, bi, n_bi);
    decode_kernel<<<(n_edges + bn - 1) / bn, bn, 0, stream>>>(
        ef, receivers, senders, n_edges,
        Wf[16], Wf[17], Wf[18], Wf[19], (float*)d_out);
}

// Round 4
// 867.758 us; speedup vs baseline: 5.2583x; 1.2395x over previous
//
#include <hip/hip_runtime.h>
#include <hip/hip_bf16.h>

#define H 16
#define NW 20
#define SCAN_TILE 2048  // 256 threads * 8 elems

__device__ __forceinline__ float bf2f(unsigned short u) {
    union { unsigned int u; float f; } c; c.u = ((unsigned int)u) << 16; return c.f;
}

__device__ __forceinline__ float bf_round(float f) {
    return __bfloat162float(__float2bfloat16(f));
}

// ---------------- weight conversion: bf16 -> f32 staging ----------------
struct WPtrs { const unsigned short* src[NW]; int len[NW]; int off[NW]; };

__global__ void cvt_weights_kernel(WPtrs p, float* __restrict__ dst) {
    int a = blockIdx.x;
    const unsigned short* s = p.src[a];
    float* d = dst + p.off[a];
    int n = p.len[a];
    for (int t = threadIdx.x; t < n; t += blockDim.x) d[t] = bf2f(s[t]);
}

// ---------------- encoder: scalar -> h -> h MLP ----------------
__global__ __launch_bounds__(256) void encode_kernel(
    const unsigned short* __restrict__ xin, int n,
    const float* __restrict__ W1, const float* __restrict__ b1,
    const float* __restrict__ W2, const float* __restrict__ b2,
    float* __restrict__ out)
{
    int i = blockIdx.x * blockDim.x + threadIdx.x;
    if (i >= n) return;
    float v = bf2f(xin[i]);
    float h[H];
    #pragma unroll
    for (int o = 0; o < H; ++o) {
        float t = W1[o] * v + b1[o];
        h[o] = t > 0.f ? t : 0.f;
    }
    float acc[H];
    #pragma unroll
    for (int o = 0; o < H; ++o) acc[o] = b2[o];
    #pragma unroll
    for (int k = 0; k < H; ++k) {
        float hk = h[k];
        #pragma unroll
        for (int o = 0; o < H; ++o) acc[o] += W2[o * H + k] * hk;
    }
    float4* dst = (float4*)(out + (size_t)i * H);
    dst[0] = make_float4(acc[0], acc[1], acc[2], acc[3]);
    dst[1] = make_float4(acc[4], acc[5], acc[6], acc[7]);
    dst[2] = make_float4(acc[8], acc[9], acc[10], acc[11]);
    dst[3] = make_float4(acc[12], acc[13], acc[14], acc[15]);
}

// ---------------- CSR build: histogram -> 3-pass scan -> fill ----------------
__global__ __launch_bounds__(256) void hist_kernel(
    const int* __restrict__ recv, int n_edges, int* __restrict__ cnt)
{
    int e = blockIdx.x * blockDim.x + threadIdx.x;
    if (e < n_edges) atomicAdd(&cnt[recv[e]], 1);
}

__global__ __launch_bounds__(256) void scan_part_kernel(
    const int* __restrict__ cnt, int n, int* __restrict__ blocksum)
{
    int base = blockIdx.x * SCAN_TILE + threadIdx.x * 8;
    int s = 0;
    #pragma unroll
    for (int k = 0; k < 8; ++k) { int i = base + k; if (i < n) s += cnt[i]; }
    __shared__ int red[256];
    red[threadIdx.x] = s;
    __syncthreads();
    for (int off = 128; off > 0; off >>= 1) {
        if (threadIdx.x < off) red[threadIdx.x] += red[threadIdx.x + off];
        __syncthreads();
    }
    if (threadIdx.x == 0) blocksum[blockIdx.x] = red[0];
}

// nb <= 1024 blocksums: exclusive-scan in place; also writes row_start[n]=total
__global__ __launch_bounds__(1024) void scan_blocksums_kernel(
    int* __restrict__ blocksum, int nb, int n, int* __restrict__ row_start)
{
    __shared__ int sums[1024];
    int t = threadIdx.x;
    int v = (t < nb) ? blocksum[t] : 0;
    sums[t] = v;
    __syncthreads();
    for (int off = 1; off < 1024; off <<= 1) {
        int u = (t >= off) ? sums[t - off] : 0;
        __syncthreads();
        sums[t] += u;
        __syncthreads();
    }
    if (t < nb) blocksum[t] = sums[t] - v;  // exclusive base per block
    if (t == 1023) row_start[n] = sums[1023];
}

__global__ __launch_bounds__(256) void scan_final_kernel(
    const int* __restrict__ cnt, int n, const int* __restrict__ blocksum,
    int* __restrict__ row_start, int* __restrict__ cursor)
{
    int t = threadIdx.x;
    int base = blockIdx.x * SCAN_TILE + t * 8;
    int loc[8]; int s = 0;
    #pragma unroll
    for (int k = 0; k < 8; ++k) { int i = base + k; loc[k] = (i < n) ? cnt[i] : 0; s += loc[k]; }
    __shared__ int sums[256];
    sums[t] = s;
    __syncthreads();
    for (int off = 1; off < 256; off <<= 1) {
        int u = (t >= off) ? sums[t - off] : 0;
        __syncthreads();
        sums[t] += u;
        __syncthreads();
    }
    int run = blocksum[blockIdx.x] + sums[t] - s;
    #pragma unroll
    for (int k = 0; k < 8; ++k) {
        int i = base + k;
        if (i < n) { row_start[i] = run; cursor[i] = run; run += loc[k]; }
    }
}

__global__ __launch_bounds__(256) void fill_kernel(
    const int* __restrict__ recv, int n_edges,
    int* __restrict__ cursor, int* __restrict__ elist)
{
    int e = blockIdx.x * blockDim.x + threadIdx.x;
    if (e >= n_edges) return;
    int pos = atomicAdd(&cursor[recv[e]], 1);
    elist[pos] = e;
}

// ---------------- edge update: MLP(concat[nf_s, nf_r, ef]), no scatter ----------------
__global__ __launch_bounds__(256) void edge_update_kernel(
    const float* __restrict__ nf, float* __restrict__ ef,
    const int* __restrict__ senders, const int* __restrict__ recv, int n_edges,
    const float* __restrict__ W1, const float* __restrict__ b1,
    const float* __restrict__ W2, const float* __restrict__ b2)
{
    int e = blockIdx.x * blockDim.x + threadIdx.x;
    if (e >= n_edges) return;
    int s = senders[e], r = recv[e];
    float x[3 * H];
    const float4* ps = (const float4*)(nf + (size_t)s * H);
    const float4* pr = (const float4*)(nf + (size_t)r * H);
    const float4* pe = (const float4*)(ef + (size_t)e * H);
    #pragma unroll
    for (int q = 0; q < 4; ++q) {
        float4 v = ps[q];
        x[q*4+0] = v.x; x[q*4+1] = v.y; x[q*4+2] = v.z; x[q*4+3] = v.w;
    }
    #pragma unroll
    for (int q = 0; q < 4; ++q) {
        float4 v = pr[q];
        x[16+q*4+0] = v.x; x[16+q*4+1] = v.y; x[16+q*4+2] = v.z; x[16+q*4+3] = v.w;
    }
    #pragma unroll
    for (int q = 0; q < 4; ++q) {
        float4 v = pe[q];
        x[32+q*4+0] = v.x; x[32+q*4+1] = v.y; x[32+q*4+2] = v.z; x[32+q*4+3] = v.w;
    }
    float h[H];
    #pragma unroll
    for (int o = 0; o < H; ++o) h[o] = b1[o];
    #pragma unroll
    for (int k = 0; k < 3 * H; ++k) {
        float xk = x[k];
        #pragma unroll
        for (int o = 0; o < H; ++o) h[o] += W1[o * 3 * H + k] * xk;
    }
    #pragma unroll
    for (int o = 0; o < H; ++o) h[o] = h[o] > 0.f ? h[o] : 0.f;
    float acc[H];
    #pragma unroll
    for (int o = 0; o < H; ++o) acc[o] = b2[o];
    #pragma unroll
    for (int k = 0; k < H; ++k) {
        float hk = h[k];
        #pragma unroll
        for (int o = 0; o < H; ++o) acc[o] += W2[o * H + k] * hk;
    }
    float4* dst = (float4*)(ef + (size_t)e * H);
    dst[0] = make_float4(acc[0], acc[1], acc[2], acc[3]);
    dst[1] = make_float4(acc[4], acc[5], acc[6], acc[7]);
    dst[2] = make_float4(acc[8], acc[9], acc[10], acc[11]);
    dst[3] = make_float4(acc[12], acc[13], acc[14], acc[15]);
}

// ---------------- node update: gather incoming ef via CSR, then MLP ----------------
__global__ __launch_bounds__(256) void node_update_kernel(
    float* __restrict__ nf, const float* __restrict__ ef,
    const int* __restrict__ row_start, const int* __restrict__ elist, int n_nodes,
    const float* __restrict__ W1, const float* __restrict__ b1,
    const float* __restrict__ W2, const float* __restrict__ b2)
{
    int i = blockIdx.x * blockDim.x + threadIdx.x;
    if (i >= n_nodes) return;
    int lo = row_start[i], hi = row_start[i + 1];
    float a[H];
    #pragma unroll
    for (int o = 0; o < H; ++o) a[o] = 0.f;
    for (int j = lo; j < hi; ++j) {
        int e = elist[j];
        const float4* pe = (const float4*)(ef + (size_t)e * H);
        float4 v0 = pe[0], v1 = pe[1], v2 = pe[2], v3 = pe[3];
        a[0] += v0.x; a[1] += v0.y; a[2] += v0.z; a[3] += v0.w;
        a[4] += v1.x; a[5] += v1.y; a[6] += v1.z; a[7] += v1.w;
        a[8] += v2.x; a[9] += v2.y; a[10] += v2.z; a[11] += v2.w;
        a[12] += v3.x; a[13] += v3.y; a[14] += v3.z; a[15] += v3.w;
    }
    int d = hi - lo;
    float rd = 1.0f / (float)(d > 1 ? d : 1);
    float x[2 * H];
    const float4* pn = (const float4*)(nf + (size_t)i * H);
    #pragma unroll
    for (int q = 0; q < 4; ++q) {
        float4 v = pn[q];
        x[q*4+0] = v.x; x[q*4+1] = v.y; x[q*4+2] = v.z; x[q*4+3] = v.w;
    }
    #pragma unroll
    for (int o = 0; o < H; ++o) x[16 + o] = a[o] * rd;
    float h[H];
    #pragma unroll
    for (int o = 0; o < H; ++o) h[o] = b1[o];
    #pragma unroll
    for (int k = 0; k < 2 * H; ++k) {
        float xk = x[k];
        #pragma unroll
        for (int o = 0; o < H; ++o) h[o] += W1[o * 2 * H + k] * xk;
    }
    #pragma unroll
    for (int o = 0; o < H; ++o) h[o] = h[o] > 0.f ? h[o] : 0.f;
    float acc[H];
    #pragma unroll
    for (int o = 0; o < H; ++o) acc[o] = b2[o];
    #pragma unroll
    for (int k = 0; k < H; ++k) {
        float hk = h[k];
        #pragma unroll
        for (int o = 0; o < H; ++o) acc[o] += W2[o * H + k] * hk;
    }
    float4* dst = (float4*)(nf + (size_t)i * H);
    dst[0] = make_float4(acc[0], acc[1], acc[2], acc[3]);
    dst[1] = make_float4(acc[4], acc[5], acc[6], acc[7]);
    dst[2] = make_float4(acc[8], acc[9], acc[10], acc[11]);
    dst[3] = make_float4(acc[12], acc[13], acc[14], acc[15]);
}

// ---------------- bidirectional edge averaging (in place) ----------------
__global__ __launch_bounds__(256) void bi_avg_kernel(
    float* __restrict__ ef, const int* __restrict__ bi, int n_bi)
{
    int p = blockIdx.x * blockDim.x + threadIdx.x;
    if (p >= n_bi) return;
    int i = bi[p], j = bi[n_bi + p];
    float4* pi = (float4*)(ef + (size_t)i * H);
    float4* pj = (float4*)(ef + (size_t)j * H);
    #pragma unroll
    for (int q = 0; q < 4; ++q) {
        float4 a = pi[q], b = pj[q];
        float4 m = make_float4(0.5f*(a.x+b.x), 0.5f*(a.y+b.y),
                               0.5f*(a.z+b.z), 0.5f*(a.w+b.w));
        pi[q] = m; pj[q] = m;
    }
}

// ---------------- decoder: h -> h -> 1, tril mask, emit f32 outputs ----------------
__global__ __launch_bounds__(256) void decode_kernel(
    const float* __restrict__ ef, const int* __restrict__ recv,
    const int* __restrict__ send, int n_edges,
    const float* __restrict__ W1, const float* __restrict__ b1,
    const float* __restrict__ W2, const float* __restrict__ b2,
    float* __restrict__ out)
{
    int e = blockIdx.x * blockDim.x + threadIdx.x;
    if (e >= n_edges) return;
    float x[H];
    const float4* pe = (const float4*)(ef + (size_t)e * H);
    #pragma unroll
    for (int q = 0; q < 4; ++q) {
        float4 v = pe[q];
        x[q*4+0] = v.x; x[q*4+1] = v.y; x[q*4+2] = v.z; x[q*4+3] = v.w;
    }
    float h[H];
    #pragma unroll
    for (int o = 0; o < H; ++o) h[o] = b1[o];
    #pragma unroll
    for (int k = 0; k < H; ++k) {
        float xk = x[k];
        #pragma unroll
        for (int o = 0; o < H; ++o) h[o] += W1[o * H + k] * xk;
    }
    float val = b2[0];
    #pragma unroll
    for (int k = 0; k < H; ++k) {
        float hk = h[k] > 0.f ? h[k] : 0.f;
        val += W2[k] * hk;
    }
    int r = recv[e], s = send[e];
    val = (r >= s) ? val : 0.0f;
    out[e] = val;
    out[(size_t)n_edges + e] = bf_round((float)r);
    out[2 * (size_t)n_edges + e] = bf_round((float)s);
}

// ---------------- host launcher ----------------
extern "C" void kernel_launch(void* const* d_in, const int* in_sizes, int n_in,
                              void* d_out, int out_size, void* d_ws, size_t ws_size,
                              hipStream_t stream) {
    const unsigned short* nodes = (const unsigned short*)d_in[0];
    const unsigned short* edges = (const unsigned short*)d_in[1];
    const int* receivers = (const int*)d_in[2];
    const int* senders   = (const int*)d_in[3];
    const int* bi        = (const int*)d_in[4];
    const int n_nodes = in_sizes[0];
    const int n_edges = in_sizes[1];
    const int n_bi    = in_sizes[4] / 2;

    static const int wl[NW] = {16,16,256,16, 16,16,256,16,
                               3840,80,1280,80, 2560,80,1280,80,
                               256,16,16,1};
    WPtrs wp;
    {
        int off = 0;
        for (int a = 0; a < NW; ++a) {
            wp.src[a] = (const unsigned short*)d_in[5 + a];
            wp.len[a] = wl[a];
            wp.off[a] = off;
            off += wl[a];
        }
    }
    float* wf = (float*)d_ws;
    const float* Wf[NW];
    for (int a = 0; a < NW; ++a) Wf[a] = wf + wp.off[a];

    float* nf  = wf + 10240;                       // [n_nodes][16] f32
    float* ef  = nf + (size_t)n_nodes * H;         // [n_edges][16] f32
    int* cnt       = (int*)(ef + (size_t)n_edges * H); // [n_nodes]
    int* row_start = cnt + n_nodes;                // [n_nodes+1]
    int* cursor    = row_start + n_nodes + 1;      // [n_nodes]
    int* elist     = cursor + n_nodes;             // [n_edges]
    int* blocksum  = elist + n_edges;              // [<=1024]

    const int bn = 256;
    const int nb_scan = (n_nodes + SCAN_TILE - 1) / SCAN_TILE;  // 49 for 100k

    cvt_weights_kernel<<<NW, 256, 0, stream>>>(wp, wf);
    encode_kernel<<<(n_nodes + bn - 1) / bn, bn, 0, stream>>>(
        nodes, n_nodes, Wf[0], Wf[1], Wf[2], Wf[3], nf);
    encode_kernel<<<(n_edges + bn - 1) / bn, bn, 0, stream>>>(
        edges, n_edges, Wf[4], Wf[5], Wf[6], Wf[7], ef);

    // CSR build (once per launch; receivers are fixed input)
    hipMemsetAsync(cnt, 0, (size_t)n_nodes * 4, stream);
    hist_kernel<<<(n_edges + bn - 1) / bn, bn, 0, stream>>>(receivers, n_edges, cnt);
    scan_part_kernel<<<nb_scan, 256, 0, stream>>>(cnt, n_nodes, blocksum);
    scan_blocksums_kernel<<<1, 1024, 0, stream>>>(blocksum, nb_scan, n_nodes, row_start);
    scan_final_kernel<<<nb_scan, 256, 0, stream>>>(cnt, n_nodes, blocksum, row_start, cursor);
    fill_kernel<<<(n_edges + bn - 1) / bn, bn, 0, stream>>>(receivers, n_edges, cursor, elist);

    for (int r = 0; r < 5; ++r) {
        edge_update_kernel<<<(n_edges + bn - 1) / bn, bn, 0, stream>>>(
            nf, ef, senders, receivers, n_edges,
            Wf[8] + r * 3 * H * H, Wf[9] + r * H,
            Wf[10] + r * H * H,    Wf[11] + r * H);
        node_update_kernel<<<(n_nodes + bn - 1) / bn, bn, 0, stream>>>(
            nf, ef, row_start, elist, n_nodes,
            Wf[12] + r * 2 * H * H, Wf[13] + r * H,
            Wf[14] + r * H * H,     Wf[15] + r * H);
    }

    bi_avg_kernel<<<(n_bi + bn - 1) / bn, bn, 0, stream>>>(ef, bi, n_bi);
    decode_kernel<<<(n_edges + bn - 1) / bn, bn, 0, stream>>>(
        ef, receivers, senders, n_edges,
        Wf[16], Wf[17], Wf[18], Wf[19], (float*)d_out);
}